// Round 14
// baseline (188.479 us; speedup 1.0000x reference)
//
#include <hip/hip_runtime.h>
#include <hip/hip_bf16.h>

#define DDIM 128
#define RDIM 32
#define PBLK 256
#define BLK  256    // 4 waves
#define CAP  144    // graph rows cached in LDS (bf16)
#define XS2  136    // x2s row stride u16 (272 B)
#define HSTR 40

typedef __attribute__((ext_vector_type(8))) short bf16x8;
typedef __attribute__((ext_vector_type(4))) float f32x4;

__device__ __forceinline__ float tanh_fast(float v) {
  float e = __expf(2.f * v);
  return 1.f - 2.f * __builtin_amdgcn_rcpf(e + 1.f);
}
__device__ __forceinline__ float sigmoid_fast(float v) {
  return __builtin_amdgcn_rcpf(1.f + __expf(-v));
}
__device__ __forceinline__ unsigned short f2bf(float f) {
  unsigned u = __float_as_uint(f);
  u += 0x7fffu + ((u >> 16) & 1u);
  return (unsigned short)(u >> 16);
}
__device__ __forceinline__ float bf2f(unsigned short s) {
  return __uint_as_float(((unsigned)s) << 16);
}
__device__ __forceinline__ unsigned pkbf(float lo, float hi) {
  __hip_bfloat162 t2 = __float22bfloat162_rn(make_float2(lo, hi));
  return *reinterpret_cast<unsigned*>(&t2);
}
__device__ __forceinline__ int lower_bound(const int* __restrict__ b, int n, int v) {
  int lo = 0, hi = n;
  while (lo < hi) { int m = (lo + hi) >> 1; if (b[m] < v) lo = m + 1; else hi = m; }
  return lo;
}

// ---------------------------------------------------------------------------
// K0: bf16 A-fragments of W1^T / W2^T. A-frag: row=l&15, k=(l>>4)*8+j.
// ---------------------------------------------------------------------------
__global__ void k0_prep(const float* __restrict__ w1, const float* __restrict__ w2,
                        unsigned short* __restrict__ w1tf, unsigned short* __restrict__ w2tf)
{
  const int i  = blockIdx.x * blockDim.x + threadIdx.x;   // 0..1023
  const int l  = i & 63;
  const int lr = l & 15, q = l >> 4;
  if (i < 512) {
    const int frag = i >> 6;             // mt2*4+kk
    const int mt2 = frag >> 2, kk = frag & 3;
    bf16x8 v;
    #pragma unroll
    for (int j = 0; j < 8; ++j)
      v[j] = (short)f2bf(w1[(size_t)(kk * 32 + q * 8 + j) * RDIM + mt2 * 16 + lr]);
    *(bf16x8*)&w1tf[(size_t)i * 8] = v;
  } else {
    const int mt = (i - 512) >> 6;
    bf16x8 v;
    #pragma unroll
    for (int j = 0; j < 8; ++j)
      v[j] = (short)f2bf(w2[(size_t)(q * 8 + j) * DDIM + mt * 16 + lr]);
    *(bf16x8*)&w2tf[(size_t)(i - 512) * 8] = v;
  }
}

__global__ void kb_bounds(const int* __restrict__ batch, int* __restrict__ bounds,
                          int N, int G)
{
  const int g = blockIdx.x * blockDim.x + threadIdx.x;
  if (g <= G) bounds[g] = lower_bound(batch, N, g);
}

// ---------------------------------------------------------------------------
// K_FUSED v3: one block (4 waves) per graph, software-pipelined loads.
// Per 16-row tile: issue ALL 16 loads (xf raw + xg) at tile start; prefetch
// next tile into the alternate named buffer while computing. Gate uses xg
// regs (no post-MFMA load). x read once; x2 cached in LDS (CAP rows);
// overflow recomputed in pass2b.
// ---------------------------------------------------------------------------
__global__ __launch_bounds__(BLK, 2) void k_fused(
    const float* __restrict__ x,
    const unsigned short* __restrict__ w1tf, const float* __restrict__ b1,
    const unsigned short* __restrict__ w2tf, const float* __restrict__ b2,
    const float* __restrict__ W, const int* __restrict__ bounds,
    float* __restrict__ out, int N)
{
  __shared__ unsigned short w1t[512 * 8];        //  8,192 B
  __shared__ unsigned short w2t[512 * 8];        //  8,192 B
  __shared__ unsigned short x2s[CAP * XS2];      // 39,168 B
  __shared__ unsigned short hs4[4][16 * HSTR];   //  5,120 B
  __shared__ float part[4][132];                 //  2,112 B
  __shared__ float meanv[DDIM];                  //    512 B
  __shared__ float tgs[DDIM];                    //    512 B  (63,808 total)

  const int t  = threadIdx.x;
  const int l  = t & 63;
  const int w  = t >> 6;          // wave 0..3
  const int lr = l & 15;
  const int q  = l >> 4;
  const int g  = blockIdx.x;
  const int lo = bounds[g], hi = bounds[g + 1];
  const int cnt = hi - lo;
  unsigned short* hs = hs4[w];

  for (int i = t; i < 512; i += BLK) {
    ((bf16x8*)w1t)[i] = ((const bf16x8*)w1tf)[i];
    ((bf16x8*)w2t)[i] = ((const bf16x8*)w2tf)[i];
  }
  __syncthreads();

  // ---- issue all 16 loads for a tile: xf raw (8 f4) + xg (8 f4) ----
  auto issue = [&](int tb, float4 (&xfr)[8], float4 (&xg)[8]) {
    const int ridx = tb + lr;
    const int rcl  = (cnt > 0) ? min(ridx, cnt - 1) : 0;
    const float* xrow = x + (size_t)(lo + rcl) * DDIM;
    #pragma unroll
    for (int kk = 0; kk < 4; ++kk) {
      xfr[kk * 2]     = *(const float4*)(xrow + kk * 32 + q * 8);
      xfr[kk * 2 + 1] = *(const float4*)(xrow + kk * 32 + q * 8 + 4);
    }
    #pragma unroll
    for (int mt = 0; mt < 8; ++mt)
      xg[mt] = *(const float4*)(xrow + mt * 16 + q * 4);
  };

  // ---- full MLP on a staged tile -> gated y (fp32), from regs only ----
  auto compute = [&](const float4 (&xfr)[8], const float4 (&xg)[8],
                     float (&y)[8][4]) {
    bf16x8 xf[4];
    #pragma unroll
    for (int kk = 0; kk < 4; ++kk) {
      uint4 u;
      u.x = pkbf(xfr[kk*2].x,   xfr[kk*2].y);
      u.y = pkbf(xfr[kk*2].z,   xfr[kk*2].w);
      u.z = pkbf(xfr[kk*2+1].x, xfr[kk*2+1].y);
      u.w = pkbf(xfr[kk*2+1].z, xfr[kk*2+1].w);
      xf[kk] = *(bf16x8*)&u;
    }
    f32x4 hacc[2];
    {
      float4 bv0 = *(const float4*)(b1 + q * 4);
      float4 bv1 = *(const float4*)(b1 + 16 + q * 4);
      hacc[0][0] = bv0.x; hacc[0][1] = bv0.y; hacc[0][2] = bv0.z; hacc[0][3] = bv0.w;
      hacc[1][0] = bv1.x; hacc[1][1] = bv1.y; hacc[1][2] = bv1.z; hacc[1][3] = bv1.w;
    }
    #pragma unroll
    for (int kk = 0; kk < 4; ++kk) {
      bf16x8 wa = *(const bf16x8*)&w1t[(size_t)((0 * 4 + kk) * 64 + l) * 8];
      bf16x8 wb = *(const bf16x8*)&w1t[(size_t)((1 * 4 + kk) * 64 + l) * 8];
      hacc[0] = __builtin_amdgcn_mfma_f32_16x16x32_bf16(wa, xf[kk], hacc[0], 0, 0, 0);
      hacc[1] = __builtin_amdgcn_mfma_f32_16x16x32_bf16(wb, xf[kk], hacc[1], 0, 0, 0);
    }
    #pragma unroll
    for (int mt2 = 0; mt2 < 2; ++mt2) {
      float h0 = fmaxf(hacc[mt2][0], 0.f), h1 = fmaxf(hacc[mt2][1], 0.f);
      float h2 = fmaxf(hacc[mt2][2], 0.f), h3 = fmaxf(hacc[mt2][3], 0.f);
      uint2 p; p.x = pkbf(h0, h1); p.y = pkbf(h2, h3);
      *(uint2*)&hs[lr * HSTR + mt2 * 16 + q * 4] = p;
    }
    bf16x8 ah = *(const bf16x8*)&hs[lr * HSTR + q * 8];
    f32x4 cacc[8];
    #pragma unroll
    for (int mt = 0; mt < 8; ++mt) {
      float4 bv = *(const float4*)(b2 + mt * 16 + q * 4);
      cacc[mt][0] = bv.x; cacc[mt][1] = bv.y; cacc[mt][2] = bv.z; cacc[mt][3] = bv.w;
    }
    #pragma unroll
    for (int mt = 0; mt < 8; ++mt) {
      bf16x8 wf = *(const bf16x8*)&w2t[(size_t)(mt * 64 + l) * 8];
      cacc[mt] = __builtin_amdgcn_mfma_f32_16x16x32_bf16(wf, ah, cacc[mt], 0, 0, 0);
    }
    #pragma unroll
    for (int mt = 0; mt < 8; ++mt) {
      y[mt][0] = xg[mt].x * (1.f + tanh_fast(cacc[mt][0]));
      y[mt][1] = xg[mt].y * (1.f + tanh_fast(cacc[mt][1]));
      y[mt][2] = xg[mt].z * (1.f + tanh_fast(cacc[mt][2]));
      y[mt][3] = xg[mt].w * (1.f + tanh_fast(cacc[mt][3]));
    }
  };

  // ---- PASS 1: pipelined MLP; accumulate mean; cache x2 to LDS ----
  float macc[8][4];
  #pragma unroll
  for (int mt = 0; mt < 8; ++mt)
    #pragma unroll
    for (int c = 0; c < 4; ++c) macc[mt][c] = 0.f;

  auto p1tail = [&](int tb, float (&y)[8][4]) {
    const int ridx = tb + lr;
    if (ridx < cnt) {
      #pragma unroll
      for (int mt = 0; mt < 8; ++mt) {
        macc[mt][0] += y[mt][0]; macc[mt][1] += y[mt][1];
        macc[mt][2] += y[mt][2]; macc[mt][3] += y[mt][3];
        if (ridx < CAP) {
          uint2 p; p.x = pkbf(y[mt][0], y[mt][1]); p.y = pkbf(y[mt][2], y[mt][3]);
          *(uint2*)&x2s[ridx * XS2 + mt * 16 + q * 4] = p;
        }
      }
    }
  };

  {
    const int niter = (cnt + 63) >> 6;          // tiles of 64 rows; wave does 16
    float4 xfA[8], xgA[8], xfB[8], xgB[8];
    float y[8][4];
    int it = 0;
    if (it < niter && it * 64 + w * 16 < cnt) issue(it * 64 + w * 16, xfA, xgA);
    while (it < niter) {
      // even -> consume A, prefetch B
      {
        const int tb = it * 64 + w * 16;
        const int tn = (it + 1) * 64 + w * 16;
        if (it + 1 < niter && tn < cnt) issue(tn, xfB, xgB);
        if (tb < cnt) { compute(xfA, xgA, y); p1tail(tb, y); }
        ++it;
      }
      if (it >= niter) break;
      // odd -> consume B, prefetch A
      {
        const int tb = it * 64 + w * 16;
        const int tn = (it + 1) * 64 + w * 16;
        if (it + 1 < niter && tn < cnt) issue(tn, xfA, xgA);
        if (tb < cnt) { compute(xfB, xgB, y); p1tail(tb, y); }
        ++it;
      }
    }
  }
  __syncthreads();

  // ---- mean reduce ----
  #pragma unroll
  for (int mt = 0; mt < 8; ++mt)
    #pragma unroll
    for (int c = 0; c < 4; ++c) {
      float v = macc[mt][c];
      v += __shfl_xor(v, 1, 64);
      v += __shfl_xor(v, 2, 64);
      v += __shfl_xor(v, 4, 64);
      v += __shfl_xor(v, 8, 64);
      macc[mt][c] = v;
    }
  if (lr == 0) {
    #pragma unroll
    for (int mt = 0; mt < 8; ++mt)
      *(float4*)&part[w][mt * 16 + q * 4] =
          make_float4(macc[mt][0], macc[mt][1], macc[mt][2], macc[mt][3]);
  }
  __syncthreads();
  if (t < DDIM) {
    float m = part[0][t] + part[1][t] + part[2][t] + part[3][t];
    meanv[t] = (cnt > 0) ? m / (float)cnt : 0.f;
  }
  __syncthreads();

  // ---- tg = tanh(mean @ W): 2 thr/col x 64 k, coalesced ----
  {
    const int c = t & 127, s = t >> 7;          // s = 0..1
    float a = 0.f;
    #pragma unroll 8
    for (int k = 0; k < 64; ++k)
      a = fmaf(meanv[s * 64 + k], W[(size_t)(s * 64 + k) * DDIM + c], a);
    part[s][c] = a;
  }
  __syncthreads();
  if (t < DDIM) tgs[t] = tanh_fast(part[0][t] + part[1][t]);
  __syncthreads();

  // ---- PASS 2a: cached rows from LDS ----
  float oacc[8][4];
  #pragma unroll
  for (int mt = 0; mt < 8; ++mt)
    #pragma unroll
    for (int c = 0; c < 4; ++c) oacc[mt][c] = 0.f;

  const int cap2 = cnt < CAP ? cnt : CAP;
  for (int it = 0; it * 64 < cap2; ++it) {
    const int tb = it * 64 + w * 16;
    if (tb >= cap2) continue;
    const int ridx = tb + lr;
    const bool v = ridx < cap2;
    const int rr = v ? ridx : 0;
    float xv[8][4];
    float p = 0.f;
    #pragma unroll
    for (int mt = 0; mt < 8; ++mt) {
      uint2 u = *(const uint2*)&x2s[rr * XS2 + mt * 16 + q * 4];
      xv[mt][0] = bf2f((unsigned short)(u.x & 0xffffu));
      xv[mt][1] = bf2f((unsigned short)(u.x >> 16));
      xv[mt][2] = bf2f((unsigned short)(u.y & 0xffffu));
      xv[mt][3] = bf2f((unsigned short)(u.y >> 16));
      float4 tg4 = *(const float4*)&tgs[mt * 16 + q * 4];
      p = fmaf(xv[mt][0], tg4.x, p); p = fmaf(xv[mt][1], tg4.y, p);
      p = fmaf(xv[mt][2], tg4.z, p); p = fmaf(xv[mt][3], tg4.w, p);
    }
    p += __shfl_xor(p, 16, 64);
    p += __shfl_xor(p, 32, 64);
    const float coef = sigmoid_fast(p);
    if (v) {
      #pragma unroll
      for (int mt = 0; mt < 8; ++mt)
        #pragma unroll
        for (int c = 0; c < 4; ++c) oacc[mt][c] = fmaf(coef, xv[mt][c], oacc[mt][c]);
    }
  }

  // ---- PASS 2b: overflow rows recomputed (pipelined same way) ----
  if (cnt > CAP) {
    const int niter = (cnt - CAP + 63) >> 6;
    float4 xfA[8], xgA[8], xfB[8], xgB[8];
    float y[8][4];
    auto p2tail = [&](int tb, float (&yy)[8][4]) {
      const int ridx = tb + lr;
      const bool v = ridx < cnt;
      float p = 0.f;
      #pragma unroll
      for (int mt = 0; mt < 8; ++mt) {
        float4 tg4 = *(const float4*)&tgs[mt * 16 + q * 4];
        p = fmaf(yy[mt][0], tg4.x, p); p = fmaf(yy[mt][1], tg4.y, p);
        p = fmaf(yy[mt][2], tg4.z, p); p = fmaf(yy[mt][3], tg4.w, p);
      }
      if (!v) p = 0.f;
      p += __shfl_xor(p, 16, 64);
      p += __shfl_xor(p, 32, 64);
      const float coef = sigmoid_fast(p);
      if (v) {
        #pragma unroll
        for (int mt = 0; mt < 8; ++mt) {
          // bf16-round y to match cached-row precision
          oacc[mt][0] = fmaf(coef, bf2f(f2bf(yy[mt][0])), oacc[mt][0]);
          oacc[mt][1] = fmaf(coef, bf2f(f2bf(yy[mt][1])), oacc[mt][1]);
          oacc[mt][2] = fmaf(coef, bf2f(f2bf(yy[mt][2])), oacc[mt][2]);
          oacc[mt][3] = fmaf(coef, bf2f(f2bf(yy[mt][3])), oacc[mt][3]);
        }
      }
    };
    int it = 0;
    if (it < niter && CAP + it * 64 + w * 16 < cnt)
      issue(CAP + it * 64 + w * 16, xfA, xgA);
    while (it < niter) {
      {
        const int tb = CAP + it * 64 + w * 16;
        const int tn = CAP + (it + 1) * 64 + w * 16;
        if (it + 1 < niter && tn < cnt) issue(tn, xfB, xgB);
        if (tb < cnt) { compute(xfA, xgA, y); p2tail(tb, y); }
        ++it;
      }
      if (it >= niter) break;
      {
        const int tb = CAP + it * 64 + w * 16;
        const int tn = CAP + (it + 1) * 64 + w * 16;
        if (it + 1 < niter && tn < cnt) issue(tn, xfA, xgA);
        if (tb < cnt) { compute(xfB, xgB, y); p2tail(tb, y); }
        ++it;
      }
    }
  }
  __syncthreads();

  // ---- out reduce ----
  #pragma unroll
  for (int mt = 0; mt < 8; ++mt)
    #pragma unroll
    for (int c = 0; c < 4; ++c) {
      float v = oacc[mt][c];
      v += __shfl_xor(v, 1, 64);
      v += __shfl_xor(v, 2, 64);
      v += __shfl_xor(v, 4, 64);
      v += __shfl_xor(v, 8, 64);
      oacc[mt][c] = v;
    }
  if (lr == 0) {
    #pragma unroll
    for (int mt = 0; mt < 8; ++mt)
      *(float4*)&part[w][mt * 16 + q * 4] =
          make_float4(oacc[mt][0], oacc[mt][1], oacc[mt][2], oacc[mt][3]);
  }
  __syncthreads();
  if (t < DDIM)
    out[(size_t)g * DDIM + t] = part[0][t] + part[1][t] + part[2][t] + part[3][t];
}

// ---------------------------------------------------------------------------
extern "C" void kernel_launch(void* const* d_in, const int* in_sizes, int n_in,
                              void* d_out, int out_size, void* d_ws, size_t ws_size,
                              hipStream_t stream) {
  const float* x     = (const float*)d_in[0];
  const int*   batch = (const int*)d_in[1];
  const float* w1 = (const float*)d_in[3];
  const float* b1 = (const float*)d_in[4];
  const float* w2 = (const float*)d_in[5];
  const float* b2 = (const float*)d_in[6];
  const float* W  = (const float*)d_in[7];
  float* out = (float*)d_out;

  const int N = in_sizes[0] / DDIM;
  const int G = out_size / DDIM;

  unsigned short* w1tf = (unsigned short*)d_ws;
  unsigned short* w2tf = w1tf + 4096;
  int* bounds = (int*)(w2tf + 4096);
  (void)ws_size; (void)n_in;

  hipLaunchKernelGGL(k0_prep, dim3(4), dim3(PBLK), 0, stream, w1, w2, w1tf, w2tf);
  hipLaunchKernelGGL(kb_bounds, dim3((G + 1 + PBLK - 1) / PBLK), dim3(PBLK), 0, stream,
                     batch, bounds, N, G);
  hipLaunchKernelGGL(k_fused, dim3(G), dim3(BLK), 0, stream,
                     x, w1tf, b1, w2tf, b2, W, bounds, out, N);
}

// Round 15
// 145.504 us; speedup vs baseline: 1.2954x; 1.2954x over previous
//
#include <hip/hip_runtime.h>
#include <hip/hip_bf16.h>

#define DDIM 128
#define RDIM 32
#define PBLK 256
#define BLK  256      // K1: 4 waves
#define HSTR 40       // hs row stride u16
#define RPB  512      // rows per K1 block (32 tiles of 16)

typedef __attribute__((ext_vector_type(8))) short bf16x8;
typedef __attribute__((ext_vector_type(4))) float f32x4;

__device__ __forceinline__ float tanh_fast(float v) {
  float e = __expf(2.f * v);
  return 1.f - 2.f * __builtin_amdgcn_rcpf(e + 1.f);
}
__device__ __forceinline__ float sigmoid_fast(float v) {
  return __builtin_amdgcn_rcpf(1.f + __expf(-v));
}
__device__ __forceinline__ unsigned short f2bf(float f) {  // RNE f32->bf16
  unsigned u = __float_as_uint(f);
  u += 0x7fffu + ((u >> 16) & 1u);
  return (unsigned short)(u >> 16);
}
__device__ __forceinline__ float bf2f(unsigned short s) {
  return __uint_as_float(((unsigned)s) << 16);
}
__device__ __forceinline__ unsigned pkbf(float lo, float hi) {
  __hip_bfloat162 t2 = __float22bfloat162_rn(make_float2(lo, hi));
  return *reinterpret_cast<unsigned*>(&t2);
}
__device__ __forceinline__ int lower_bound(const int* __restrict__ b, int n, int v) {
  int lo = 0, hi = n;
  while (lo < hi) { int m = (lo + hi) >> 1; if (b[m] < v) lo = m + 1; else hi = m; }
  return lo;
}

// ---------------------------------------------------------------------------
// K0: bf16 A-fragments of W1^T / W2^T. A-frag: row=l&15, k=(l>>4)*8+j.
// ---------------------------------------------------------------------------
__global__ void k0_prep(const float* __restrict__ w1, const float* __restrict__ w2,
                        unsigned short* __restrict__ w1tf, unsigned short* __restrict__ w2tf)
{
  const int i  = blockIdx.x * blockDim.x + threadIdx.x;   // 0..1023
  const int l  = i & 63;
  const int lr = l & 15, q = l >> 4;
  if (i < 512) {
    const int frag = i >> 6;             // mt2*4+kk
    const int mt2 = frag >> 2, kk = frag & 3;
    bf16x8 v;
    #pragma unroll
    for (int j = 0; j < 8; ++j)
      v[j] = (short)f2bf(w1[(size_t)(kk * 32 + q * 8 + j) * RDIM + mt2 * 16 + lr]);
    *(bf16x8*)&w1tf[(size_t)i * 8] = v;
  } else {
    const int mt = (i - 512) >> 6;
    bf16x8 v;
    #pragma unroll
    for (int j = 0; j < 8; ++j)
      v[j] = (short)f2bf(w2[(size_t)(q * 8 + j) * DDIM + mt * 16 + lr]);
    *(bf16x8*)&w2tf[(size_t)(i - 512) * 8] = v;
  }
}

__global__ void kb_bounds(const int* __restrict__ batch, int* __restrict__ bounds,
                          int N, int G)
{
  const int g = blockIdx.x * blockDim.x + threadIdx.x;
  if (g <= G) bounds[g] = lower_bound(batch, N, g);
}

// ---------------------------------------------------------------------------
// K1 (async-staged MLP): x2 = x*(1+tanh(relu(x@W1+b1)@W2+b2)) -> bf16.
// Per wave: 2-slot LDS ring; slot = 16 rows x 128 f32 (8KB), filled by 8
// global_load_lds(16B) with chunk-XOR swizzle applied on the SOURCE address
// (DMA dest is linear); all slot reads apply the same swizzle. Counted
// s_waitcnt vmcnt(8) keeps next tile's fills in flight across compute.
// Transposed MFMA core (C/D col = node); gate reads fp32 x from slot; y
// (bf16) written back into row-local slot bytes, then contiguous 1KB stores.
// ---------------------------------------------------------------------------
__global__ __launch_bounds__(BLK, 2) void k1_mlp(
    const float* __restrict__ x,
    const unsigned short* __restrict__ w1tf, const float* __restrict__ b1,
    const unsigned short* __restrict__ w2tf, const float* __restrict__ b2,
    unsigned short* __restrict__ x2, int N)
{
  __shared__ float ring[4][2][2048];             // 65,536 B
  __shared__ unsigned short hs4[4][16 * HSTR];   //  5,120 B  (70,656 total)

  const int t  = threadIdx.x;
  const int l  = t & 63;
  const int w  = t >> 6;
  const int lr = l & 15;
  const int q  = l >> 4;
  const int rb0  = blockIdx.x * RPB;
  const int rows = min(RPB, N - rb0);
  if (rows <= 0) return;
  const int ntile = (rows + 15) >> 4;
  unsigned short* hs = hs4[w];

  // ---- weight A-frags in registers (L2-hot coalesced 16B loads) ----
  bf16x8 w1r[2][4], w2r[8];
  #pragma unroll
  for (int mt2 = 0; mt2 < 2; ++mt2)
    #pragma unroll
    for (int kk = 0; kk < 4; ++kk)
      w1r[mt2][kk] = *(const bf16x8*)&w1tf[(size_t)((mt2 * 4 + kk) * 64 + l) * 8];
  #pragma unroll
  for (int mt = 0; mt < 8; ++mt)
    w2r[mt] = *(const bf16x8*)&w2tf[(size_t)(mt * 64 + l) * 8];

  const int sr = l >> 5;          // stage row parity (0/1)
  const int sc = l & 31;          // stage chunk col (16B units)
  const int swz = lr & 7;

  // ---- async fill: 8 x global_load_lds(16B); source pre-swizzled ----
  auto fill = [&](int s, int row0) {
    float* lds = ring[w][s];
    #pragma unroll
    for (int j = 0; j < 8; ++j) {
      const int r   = j * 2 + sr;
      const int row = min(row0 + r, N - 1);
      const int lc  = sc ^ (r & 7);
      const float* src = x + (size_t)row * DDIM + lc * 4;
      __builtin_amdgcn_global_load_lds(src, lds + j * 256, 16, 0, 0);
    }
  };

  // ---- compute one tile from a slot; y -> slot; contiguous store ----
  auto work = [&](int s, int row0) {
    float* lds = ring[w][s];
    // xf B-frags: row lr, logical chunks (kk*8+q*2, +1), swizzled
    bf16x8 xf[4];
    #pragma unroll
    for (int kk = 0; kk < 4; ++kk) {
      const int c0 = kk * 8 + q * 2;
      float4 a = *(const float4*)&lds[lr * 128 + ((c0    ) ^ swz) * 4];
      float4 b = *(const float4*)&lds[lr * 128 + ((c0 + 1) ^ swz) * 4];
      uint4 u;
      u.x = pkbf(a.x, a.y); u.y = pkbf(a.z, a.w);
      u.z = pkbf(b.x, b.y); u.w = pkbf(b.z, b.w);
      xf[kk] = *(bf16x8*)&u;
    }
    // phase B: H^T = W1^T @ X^T + b1
    f32x4 hacc[2];
    {
      float4 bv0 = *(const float4*)(b1 + q * 4);
      float4 bv1 = *(const float4*)(b1 + 16 + q * 4);
      hacc[0][0] = bv0.x; hacc[0][1] = bv0.y; hacc[0][2] = bv0.z; hacc[0][3] = bv0.w;
      hacc[1][0] = bv1.x; hacc[1][1] = bv1.y; hacc[1][2] = bv1.z; hacc[1][3] = bv1.w;
    }
    #pragma unroll
    for (int kk = 0; kk < 4; ++kk) {
      hacc[0] = __builtin_amdgcn_mfma_f32_16x16x32_bf16(w1r[0][kk], xf[kk], hacc[0], 0, 0, 0);
      hacc[1] = __builtin_amdgcn_mfma_f32_16x16x32_bf16(w1r[1][kk], xf[kk], hacc[1], 0, 0, 0);
    }
    // relu -> hs bounce -> H^T B-frag
    #pragma unroll
    for (int mt2 = 0; mt2 < 2; ++mt2) {
      float h0 = fmaxf(hacc[mt2][0], 0.f), h1 = fmaxf(hacc[mt2][1], 0.f);
      float h2 = fmaxf(hacc[mt2][2], 0.f), h3 = fmaxf(hacc[mt2][3], 0.f);
      uint2 p; p.x = pkbf(h0, h1); p.y = pkbf(h2, h3);
      *(uint2*)&hs[lr * HSTR + mt2 * 16 + q * 4] = p;
    }
    bf16x8 ah = *(const bf16x8*)&hs[lr * HSTR + q * 8];
    // phase C: A2^T = W2^T @ H^T + b2
    f32x4 cacc[8];
    #pragma unroll
    for (int mt = 0; mt < 8; ++mt) {
      float4 bv = *(const float4*)(b2 + mt * 16 + q * 4);
      cacc[mt][0] = bv.x; cacc[mt][1] = bv.y; cacc[mt][2] = bv.z; cacc[mt][3] = bv.w;
    }
    #pragma unroll
    for (int mt = 0; mt < 8; ++mt)
      cacc[mt] = __builtin_amdgcn_mfma_f32_16x16x32_bf16(w2r[mt], ah, cacc[mt], 0, 0, 0);
    // gate: read fp32 x chunk (4mt+q)^swz; y(bf16) -> row-local slot bytes
    #pragma unroll
    for (int mt = 0; mt < 8; ++mt) {
      float4 xg = *(const float4*)&lds[lr * 128 + ((mt * 4 + q) ^ swz) * 4];
      float y0 = xg.x * (1.f + tanh_fast(cacc[mt][0]));
      float y1 = xg.y * (1.f + tanh_fast(cacc[mt][1]));
      float y2 = xg.z * (1.f + tanh_fast(cacc[mt][2]));
      float y3 = xg.w * (1.f + tanh_fast(cacc[mt][3]));
      uint2 p; p.x = pkbf(y0, y1); p.y = pkbf(y2, y3);
      *(uint2*)((char*)lds + lr * 512 + (((mt * 2 + (q >> 1)) ^ swz) << 4)
                + ((q & 1) << 3)) = p;
    }
    // readback (swizzled) + contiguous global store (1KB/instr)
    #pragma unroll
    for (int k = 0; k < 4; ++k) {
      const int idx  = l + k * 64;
      const int node = idx >> 4, c16 = idx & 15;
      if (row0 + node < N) {
        bf16x8 v = *(const bf16x8*)((const char*)lds + node * 512
                                    + ((c16 ^ (node & 7)) << 4));
        *(bf16x8*)&x2[(size_t)(row0 + node) * DDIM + c16 * 8] = v;
      }
    }
  };

  // ---- pipelined loop over this wave's tiles (w, w+4, ...) ----
  int ti = w, cur = 0;
  if (ti < ntile) fill(cur, rb0 + ti * 16);
  for (; ti < ntile; ti += 4) {
    const int tn = ti + 4;
    if (tn < ntile) {
      fill(cur ^ 1, rb0 + tn * 16);
      asm volatile("s_waitcnt vmcnt(8)" ::: "memory");   // cur slot complete
    } else {
      asm volatile("s_waitcnt vmcnt(0)" ::: "memory");
    }
    work(cur, rb0 + ti * 16);
    cur ^= 1;
  }
}

// ---------------------------------------------------------------------------
// K2 (fused graph pass): per-graph mean -> tg=tanh(mean@W) -> coef pass.
// One block per graph; x2 is L3-hot. Bounds precomputed.
// ---------------------------------------------------------------------------
__global__ void k3_graph(
    const unsigned short* __restrict__ x2, const int* __restrict__ bounds,
    const float* __restrict__ W, float* __restrict__ out, int N)
{
  __shared__ __align__(16) float part[8][132];
  __shared__ float meanv[DDIM];
  __shared__ float tgs[DDIM];
  const int g = blockIdx.x, t = threadIdx.x;
  const int lo = bounds[g], hi = bounds[g + 1];
  const int q = t & 31, s = t >> 5;

  // ---- phase 1: segment mean ----
  {
    float acc[4] = {0.f, 0.f, 0.f, 0.f};
    for (int n = lo + s; n < hi; n += 8) {
      ushort4 u = *(const ushort4*)&x2[(size_t)n * DDIM + q * 4];
      acc[0] += bf2f(u.x); acc[1] += bf2f(u.y); acc[2] += bf2f(u.z); acc[3] += bf2f(u.w);
    }
    *(float4*)&part[s][q * 4] = make_float4(acc[0], acc[1], acc[2], acc[3]);
  }
  __syncthreads();
  if (t < DDIM) {
    float m = 0.f;
    #pragma unroll
    for (int s2 = 0; s2 < 8; ++s2) m += part[s2][t];
    float invc = (hi > lo) ? 1.f / (float)(hi - lo) : 0.f;
    meanv[t] = m * invc;
  }
  __syncthreads();

  // ---- phase 2: tg = tanh(mean @ W) ----
  if (t < DDIM) {
    float a = 0.f;
    #pragma unroll 8
    for (int k = 0; k < DDIM; ++k) a = fmaf(meanv[k], W[k * DDIM + t], a);
    tgs[t] = tanh_fast(a);
  }
  __syncthreads();

  // ---- phase 3: coefs = sigmoid(x2 . tg); out = sum coefs*x2 ----
  float4 tg4 = *(const float4*)&tgs[q * 4];
  float tga[4] = {tg4.x, tg4.y, tg4.z, tg4.w};
  float acc[4] = {0.f, 0.f, 0.f, 0.f};
  for (int n = lo + s; n < hi; n += 8) {
    ushort4 u = *(const ushort4*)&x2[(size_t)n * DDIM + q * 4];
    float xv[4] = {bf2f(u.x), bf2f(u.y), bf2f(u.z), bf2f(u.w)};
    float p = xv[0] * tga[0] + xv[1] * tga[1] + xv[2] * tga[2] + xv[3] * tga[3];
    #pragma unroll
    for (int off = 16; off >= 1; off >>= 1) p += __shfl_xor(p, off, 64);
    float coef = sigmoid_fast(p);
    #pragma unroll
    for (int c = 0; c < 4; ++c) acc[c] = fmaf(coef, xv[c], acc[c]);
  }
  *(float4*)&part[s][q * 4] = make_float4(acc[0], acc[1], acc[2], acc[3]);
  __syncthreads();

  if (t < DDIM) {
    float m = 0.f;
    #pragma unroll
    for (int s2 = 0; s2 < 8; ++s2) m += part[s2][t];
    out[(size_t)g * DDIM + t] = m;
  }
}

// ---------------------------------------------------------------------------
extern "C" void kernel_launch(void* const* d_in, const int* in_sizes, int n_in,
                              void* d_out, int out_size, void* d_ws, size_t ws_size,
                              hipStream_t stream) {
  const float* x     = (const float*)d_in[0];
  const int*   batch = (const int*)d_in[1];
  const float* w1 = (const float*)d_in[3];
  const float* b1 = (const float*)d_in[4];
  const float* w2 = (const float*)d_in[5];
  const float* b2 = (const float*)d_in[6];
  const float* W  = (const float*)d_in[7];
  float* out = (float*)d_out;

  const int N = in_sizes[0] / DDIM;
  const int G = out_size / DDIM;

  // ws: [w1tf 4096 u16][w2tf 4096 u16][bounds G+1 int pad16][x2 N*128 u16]
  unsigned short* w1tf = (unsigned short*)d_ws;
  unsigned short* w2tf = w1tf + 4096;
  int* bounds = (int*)(w2tf + 4096);
  size_t boff = (((size_t)(G + 1) * 4) + 15) & ~(size_t)15;
  unsigned short* x2 = (unsigned short*)((char*)bounds + boff);
  (void)ws_size; (void)n_in;

  hipLaunchKernelGGL(k0_prep, dim3(4), dim3(PBLK), 0, stream, w1, w2, w1tf, w2tf);
  hipLaunchKernelGGL(kb_bounds, dim3((G + 1 + PBLK - 1) / PBLK), dim3(PBLK), 0, stream,
                     batch, bounds, N, G);
  const int grid1 = (N + RPB - 1) / RPB;
  hipLaunchKernelGGL(k1_mlp, dim3(grid1), dim3(BLK), 0, stream,
                     x, w1tf, b1, w2tf, b2, x2, N);
  hipLaunchKernelGGL(k3_graph, dim3(G), dim3(BLK), 0, stream, x2, bounds, W, out, N);
}

// Round 16
// 134.263 us; speedup vs baseline: 1.4038x; 1.0837x over previous
//
#include <hip/hip_runtime.h>
#include <hip/hip_bf16.h>

#define DDIM 128
#define RDIM 32
#define PBLK 256
#define BLK  256      // 4 waves
#define HSTR 40       // hs row stride u16

typedef __attribute__((ext_vector_type(8))) short bf16x8;
typedef __attribute__((ext_vector_type(4))) float f32x4;

__device__ __forceinline__ float tanh_fast(float v) {
  float e = __expf(2.f * v);
  return 1.f - 2.f * __builtin_amdgcn_rcpf(e + 1.f);
}
__device__ __forceinline__ float sigmoid_fast(float v) {
  return __builtin_amdgcn_rcpf(1.f + __expf(-v));
}
__device__ __forceinline__ unsigned short f2bf(float f) {  // RNE f32->bf16
  unsigned u = __float_as_uint(f);
  u += 0x7fffu + ((u >> 16) & 1u);
  return (unsigned short)(u >> 16);
}
__device__ __forceinline__ float bf2f(unsigned short s) {
  return __uint_as_float(((unsigned)s) << 16);
}
__device__ __forceinline__ unsigned pkbf(float lo, float hi) {
  __hip_bfloat162 t2 = __float22bfloat162_rn(make_float2(lo, hi));
  return *reinterpret_cast<unsigned*>(&t2);
}
__device__ __forceinline__ int lower_bound(const int* __restrict__ b, int n, int v) {
  int lo = 0, hi = n;
  while (lo < hi) { int m = (lo + hi) >> 1; if (b[m] < v) lo = m + 1; else hi = m; }
  return lo;
}

// ---------------------------------------------------------------------------
// K0: bf16 A-fragments of W1^T / W2^T. A-frag: row=l&15, k=(l>>4)*8+j.
// ---------------------------------------------------------------------------
__global__ void k0_prep(const float* __restrict__ w1, const float* __restrict__ w2,
                        unsigned short* __restrict__ w1tf, unsigned short* __restrict__ w2tf)
{
  const int i  = blockIdx.x * blockDim.x + threadIdx.x;   // 0..1023
  const int l  = i & 63;
  const int lr = l & 15, q = l >> 4;
  if (i < 512) {
    const int frag = i >> 6;             // mt2*4+kk
    const int mt2 = frag >> 2, kk = frag & 3;
    bf16x8 v;
    #pragma unroll
    for (int j = 0; j < 8; ++j)
      v[j] = (short)f2bf(w1[(size_t)(kk * 32 + q * 8 + j) * RDIM + mt2 * 16 + lr]);
    *(bf16x8*)&w1tf[(size_t)i * 8] = v;
  } else {
    const int mt = (i - 512) >> 6;
    bf16x8 v;
    #pragma unroll
    for (int j = 0; j < 8; ++j)
      v[j] = (short)f2bf(w2[(size_t)(q * 8 + j) * DDIM + mt * 16 + lr]);
    *(bf16x8*)&w2tf[(size_t)(i - 512) * 8] = v;
  }
}

__global__ void kb_bounds(const int* __restrict__ batch, int* __restrict__ bounds,
                          int N, int G)
{
  const int g = blockIdx.x * blockDim.x + threadIdx.x;
  if (g <= G) bounds[g] = lower_bound(batch, N, g);
}

// ---------------------------------------------------------------------------
// K_FUSED v4: one block (4 waves) per graph; NO x2 materialization.
// Pass1: async-staged (R15-proven ring: 2 slots x 16 rows x 128 f32/wave,
// 8x global_load_lds(16B)/fill, counted vmcnt(8), chunk-XOR source swizzle)
// stream of graph rows -> MLP (transposed MFMA) -> register mean-accumulate.
// Reduce -> tg = tanh(mean @ W). Pass2: re-stream the same rows (L3-hot),
// recompute y, coef = sigmoid(y.tg), out-accumulate. WRITE ~= 1MB total.
// ---------------------------------------------------------------------------
__global__ __launch_bounds__(BLK, 2) void k_fused(
    const float* __restrict__ x,
    const unsigned short* __restrict__ w1tf, const float* __restrict__ b1,
    const unsigned short* __restrict__ w2tf, const float* __restrict__ b2,
    const float* __restrict__ W, const int* __restrict__ bounds,
    float* __restrict__ out, int N)
{
  __shared__ float ring[4][2][2048];             // 65,536 B
  __shared__ unsigned short hs4[4][16 * HSTR];   //  5,120 B
  __shared__ float part[4][132];                 //  2,112 B
  __shared__ float meanv[DDIM];                  //    512 B
  __shared__ float tgs[DDIM];                    //    512 B  (73,792 total)

  const int t  = threadIdx.x;
  const int l  = t & 63;
  const int w  = t >> 6;
  const int lr = l & 15;
  const int q  = l >> 4;
  const int g  = blockIdx.x;
  const int lo = bounds[g], hi = bounds[g + 1];
  const int cnt = hi - lo;
  unsigned short* hs = hs4[w];

  if (cnt <= 0) { if (t < DDIM) out[(size_t)g * DDIM + t] = 0.f; return; }

  // ---- weight A-frags in registers (proven R15; L2-hot 16B loads) ----
  bf16x8 w1r[2][4], w2r[8];
  #pragma unroll
  for (int mt2 = 0; mt2 < 2; ++mt2)
    #pragma unroll
    for (int kk = 0; kk < 4; ++kk)
      w1r[mt2][kk] = *(const bf16x8*)&w1tf[(size_t)((mt2 * 4 + kk) * 64 + l) * 8];
  #pragma unroll
  for (int mt = 0; mt < 8; ++mt)
    w2r[mt] = *(const bf16x8*)&w2tf[(size_t)(mt * 64 + l) * 8];

  const int sr  = l >> 5;        // stage row parity
  const int sc  = l & 31;        // stage 16B-chunk col
  const int swz = lr & 7;
  const int ntile = (cnt + 15) >> 4;

  // ---- async fill: 8 x global_load_lds(16B), source pre-swizzled ----
  auto fill = [&](int s, int tb) {
    float* lds = ring[w][s];
    #pragma unroll
    for (int j = 0; j < 8; ++j) {
      const int r   = j * 2 + sr;
      const int row = lo + min(tb + r, cnt - 1);      // clamp inside graph
      const int lc  = sc ^ (r & 7);
      __builtin_amdgcn_global_load_lds(x + (size_t)row * DDIM + lc * 4,
                                       lds + j * 256, 16, 0, 0);
    }
  };

  // ---- MLP on one staged tile: y[mt][c] for node lr, d=mt*16+q*4+c ----
  auto mlp = [&](int s, float (&y)[8][4]) {
    float* lds = ring[w][s];
    bf16x8 xf[4];
    #pragma unroll
    for (int kk = 0; kk < 4; ++kk) {
      const int c0 = kk * 8 + q * 2;
      float4 a = *(const float4*)&lds[lr * 128 + ((c0    ) ^ swz) * 4];
      float4 b = *(const float4*)&lds[lr * 128 + ((c0 + 1) ^ swz) * 4];
      uint4 u;
      u.x = pkbf(a.x, a.y); u.y = pkbf(a.z, a.w);
      u.z = pkbf(b.x, b.y); u.w = pkbf(b.z, b.w);
      xf[kk] = *(bf16x8*)&u;
    }
    f32x4 hacc[2];
    {
      float4 bv0 = *(const float4*)(b1 + q * 4);
      float4 bv1 = *(const float4*)(b1 + 16 + q * 4);
      hacc[0][0] = bv0.x; hacc[0][1] = bv0.y; hacc[0][2] = bv0.z; hacc[0][3] = bv0.w;
      hacc[1][0] = bv1.x; hacc[1][1] = bv1.y; hacc[1][2] = bv1.z; hacc[1][3] = bv1.w;
    }
    #pragma unroll
    for (int kk = 0; kk < 4; ++kk) {
      hacc[0] = __builtin_amdgcn_mfma_f32_16x16x32_bf16(w1r[0][kk], xf[kk], hacc[0], 0, 0, 0);
      hacc[1] = __builtin_amdgcn_mfma_f32_16x16x32_bf16(w1r[1][kk], xf[kk], hacc[1], 0, 0, 0);
    }
    #pragma unroll
    for (int mt2 = 0; mt2 < 2; ++mt2) {
      float h0 = fmaxf(hacc[mt2][0], 0.f), h1 = fmaxf(hacc[mt2][1], 0.f);
      float h2 = fmaxf(hacc[mt2][2], 0.f), h3 = fmaxf(hacc[mt2][3], 0.f);
      uint2 p; p.x = pkbf(h0, h1); p.y = pkbf(h2, h3);
      *(uint2*)&hs[lr * HSTR + mt2 * 16 + q * 4] = p;
    }
    bf16x8 ah = *(const bf16x8*)&hs[lr * HSTR + q * 8];
    f32x4 cacc[8];
    #pragma unroll
    for (int mt = 0; mt < 8; ++mt) {
      float4 bv = *(const float4*)(b2 + mt * 16 + q * 4);
      cacc[mt][0] = bv.x; cacc[mt][1] = bv.y; cacc[mt][2] = bv.z; cacc[mt][3] = bv.w;
    }
    #pragma unroll
    for (int mt = 0; mt < 8; ++mt)
      cacc[mt] = __builtin_amdgcn_mfma_f32_16x16x32_bf16(w2r[mt], ah, cacc[mt], 0, 0, 0);
    #pragma unroll
    for (int mt = 0; mt < 8; ++mt) {
      float4 xg = *(const float4*)&lds[lr * 128 + ((mt * 4 + q) ^ swz) * 4];
      y[mt][0] = xg.x * (1.f + tanh_fast(cacc[mt][0]));
      y[mt][1] = xg.y * (1.f + tanh_fast(cacc[mt][1]));
      y[mt][2] = xg.z * (1.f + tanh_fast(cacc[mt][2]));
      y[mt][3] = xg.w * (1.f + tanh_fast(cacc[mt][3]));
    }
  };

  // ================= PASS 1: mean accumulate =================
  float macc[8][4];
  #pragma unroll
  for (int mt = 0; mt < 8; ++mt)
    #pragma unroll
    for (int c = 0; c < 4; ++c) macc[mt][c] = 0.f;

  {
    int ti = w, cur = 0;
    if (ti < ntile) fill(cur, ti * 16);
    for (; ti < ntile; ti += 4) {
      const int tn = ti + 4;
      if (tn < ntile) {
        fill(cur ^ 1, tn * 16);
        asm volatile("s_waitcnt vmcnt(8)" ::: "memory");
      } else {
        asm volatile("s_waitcnt vmcnt(0)" ::: "memory");
      }
      float y[8][4];
      mlp(cur, y);
      if (ti * 16 + lr < cnt) {
        #pragma unroll
        for (int mt = 0; mt < 8; ++mt)
          #pragma unroll
          for (int c = 0; c < 4; ++c) macc[mt][c] += y[mt][c];
      }
      cur ^= 1;
    }
  }
  __syncthreads();

  // ---- mean reduce: over lr lanes (xor 1,2,4,8), cross-wave via part ----
  #pragma unroll
  for (int mt = 0; mt < 8; ++mt)
    #pragma unroll
    for (int c = 0; c < 4; ++c) {
      float v = macc[mt][c];
      v += __shfl_xor(v, 1, 64);
      v += __shfl_xor(v, 2, 64);
      v += __shfl_xor(v, 4, 64);
      v += __shfl_xor(v, 8, 64);
      macc[mt][c] = v;
    }
  if (lr == 0) {
    #pragma unroll
    for (int mt = 0; mt < 8; ++mt)
      *(float4*)&part[w][mt * 16 + q * 4] =
          make_float4(macc[mt][0], macc[mt][1], macc[mt][2], macc[mt][3]);
  }
  __syncthreads();
  if (t < DDIM) {
    float m = part[0][t] + part[1][t] + part[2][t] + part[3][t];
    meanv[t] = m / (float)cnt;
  }
  __syncthreads();

  // ---- tg = tanh(mean @ W): 2 thr/col x 64 k, coalesced ----
  {
    const int c = t & 127, s = t >> 7;
    float a = 0.f;
    #pragma unroll 8
    for (int k = 0; k < 64; ++k)
      a = fmaf(meanv[s * 64 + k], W[(size_t)(s * 64 + k) * DDIM + c], a);
    part[s][c] = a;
  }
  __syncthreads();
  if (t < DDIM) tgs[t] = tanh_fast(part[0][t] + part[1][t]);
  __syncthreads();

  // ================= PASS 2: re-stream (L3-hot), coef, out =================
  float oacc[8][4];
  #pragma unroll
  for (int mt = 0; mt < 8; ++mt)
    #pragma unroll
    for (int c = 0; c < 4; ++c) oacc[mt][c] = 0.f;

  {
    int ti = w, cur = 0;
    if (ti < ntile) fill(cur, ti * 16);
    for (; ti < ntile; ti += 4) {
      const int tn = ti + 4;
      if (tn < ntile) {
        fill(cur ^ 1, tn * 16);
        asm volatile("s_waitcnt vmcnt(8)" ::: "memory");
      } else {
        asm volatile("s_waitcnt vmcnt(0)" ::: "memory");
      }
      float y[8][4];
      mlp(cur, y);
      float p = 0.f;
      #pragma unroll
      for (int mt = 0; mt < 8; ++mt) {
        float4 tg4 = *(const float4*)&tgs[mt * 16 + q * 4];
        p = fmaf(y[mt][0], tg4.x, p); p = fmaf(y[mt][1], tg4.y, p);
        p = fmaf(y[mt][2], tg4.z, p); p = fmaf(y[mt][3], tg4.w, p);
      }
      p += __shfl_xor(p, 16, 64);
      p += __shfl_xor(p, 32, 64);
      const float coef = sigmoid_fast(p);
      if (ti * 16 + lr < cnt) {
        #pragma unroll
        for (int mt = 0; mt < 8; ++mt)
          #pragma unroll
          for (int c = 0; c < 4; ++c)
            oacc[mt][c] = fmaf(coef, y[mt][c], oacc[mt][c]);
      }
      cur ^= 1;
    }
  }
  __syncthreads();

  // ---- out reduce ----
  #pragma unroll
  for (int mt = 0; mt < 8; ++mt)
    #pragma unroll
    for (int c = 0; c < 4; ++c) {
      float v = oacc[mt][c];
      v += __shfl_xor(v, 1, 64);
      v += __shfl_xor(v, 2, 64);
      v += __shfl_xor(v, 4, 64);
      v += __shfl_xor(v, 8, 64);
      oacc[mt][c] = v;
    }
  if (lr == 0) {
    #pragma unroll
    for (int mt = 0; mt < 8; ++mt)
      *(float4*)&part[w][mt * 16 + q * 4] =
          make_float4(oacc[mt][0], oacc[mt][1], oacc[mt][2], oacc[mt][3]);
  }
  __syncthreads();
  if (t < DDIM)
    out[(size_t)g * DDIM + t] = part[0][t] + part[1][t] + part[2][t] + part[3][t];
}

// ---------------------------------------------------------------------------
extern "C" void kernel_launch(void* const* d_in, const int* in_sizes, int n_in,
                              void* d_out, int out_size, void* d_ws, size_t ws_size,
                              hipStream_t stream) {
  const float* x     = (const float*)d_in[0];
  const int*   batch = (const int*)d_in[1];
  const float* w1 = (const float*)d_in[3];
  const float* b1 = (const float*)d_in[4];
  const float* w2 = (const float*)d_in[5];
  const float* b2 = (const float*)d_in[6];
  const float* W  = (const float*)d_in[7];
  float* out = (float*)d_out;

  const int N = in_sizes[0] / DDIM;
  const int G = out_size / DDIM;

  // ws: [w1tf 4096 u16][w2tf 4096 u16][bounds G+1 int]  (no x2!)
  unsigned short* w1tf = (unsigned short*)d_ws;
  unsigned short* w2tf = w1tf + 4096;
  int* bounds = (int*)(w2tf + 4096);
  (void)ws_size; (void)n_in;

  hipLaunchKernelGGL(k0_prep, dim3(4), dim3(PBLK), 0, stream, w1, w2, w1tf, w2tf);
  hipLaunchKernelGGL(kb_bounds, dim3((G + 1 + PBLK - 1) / PBLK), dim3(PBLK), 0, stream,
                     batch, bounds, N, G);
  hipLaunchKernelGGL(k_fused, dim3(G), dim3(BLK), 0, stream,
                     x, w1tf, b1, w2tf, b2, W, bounds, out, N);
}

// Round 17
// 128.364 us; speedup vs baseline: 1.4683x; 1.0460x over previous
//
#include <hip/hip_runtime.h>
#include <hip/hip_bf16.h>

#define DDIM 128
#define RDIM 32
#define PBLK 256
#define BLK  256      // 4 waves
#define HSTR 40       // hs row stride u16

typedef __attribute__((ext_vector_type(8))) short bf16x8;
typedef __attribute__((ext_vector_type(4))) float f32x4;

__device__ __forceinline__ float tanh_fast(float v) {
  float e = __expf(2.f * v);
  return 1.f - 2.f * __builtin_amdgcn_rcpf(e + 1.f);
}
__device__ __forceinline__ float sigmoid_fast(float v) {
  return __builtin_amdgcn_rcpf(1.f + __expf(-v));
}
__device__ __forceinline__ unsigned short f2bf(float f) {  // RNE f32->bf16
  unsigned u = __float_as_uint(f);
  u += 0x7fffu + ((u >> 16) & 1u);
  return (unsigned short)(u >> 16);
}
__device__ __forceinline__ float bf2f(unsigned short s) {
  return __uint_as_float(((unsigned)s) << 16);
}
__device__ __forceinline__ unsigned pkbf(float lo, float hi) {
  __hip_bfloat162 t2 = __float22bfloat162_rn(make_float2(lo, hi));
  return *reinterpret_cast<unsigned*>(&t2);
}
__device__ __forceinline__ int lower_bound(const int* __restrict__ b, int n, int v) {
  int lo = 0, hi = n;
  while (lo < hi) { int m = (lo + hi) >> 1; if (b[m] < v) lo = m + 1; else hi = m; }
  return lo;
}

// ---------------------------------------------------------------------------
// K0: bf16 A-fragments of W1^T / W2^T. A-frag: row=l&15, k=(l>>4)*8+j.
// ---------------------------------------------------------------------------
__global__ void k0_prep(const float* __restrict__ w1, const float* __restrict__ w2,
                        unsigned short* __restrict__ w1tf, unsigned short* __restrict__ w2tf)
{
  const int i  = blockIdx.x * blockDim.x + threadIdx.x;   // 0..1023
  const int l  = i & 63;
  const int lr = l & 15, q = l >> 4;
  if (i < 512) {
    const int frag = i >> 6;             // mt2*4+kk
    const int mt2 = frag >> 2, kk = frag & 3;
    bf16x8 v;
    #pragma unroll
    for (int j = 0; j < 8; ++j)
      v[j] = (short)f2bf(w1[(size_t)(kk * 32 + q * 8 + j) * RDIM + mt2 * 16 + lr]);
    *(bf16x8*)&w1tf[(size_t)i * 8] = v;
  } else {
    const int mt = (i - 512) >> 6;
    bf16x8 v;
    #pragma unroll
    for (int j = 0; j < 8; ++j)
      v[j] = (short)f2bf(w2[(size_t)(q * 8 + j) * DDIM + mt * 16 + lr]);
    *(bf16x8*)&w2tf[(size_t)(i - 512) * 8] = v;
  }
}

__global__ void kb_bounds(const int* __restrict__ batch, int* __restrict__ bounds,
                          int N, int G)
{
  const int g = blockIdx.x * blockDim.x + threadIdx.x;
  if (g <= G) bounds[g] = lower_bound(batch, N, g);
}

// ---------------------------------------------------------------------------
// K_FUSED v5: R16 + ALL global constants hoisted out of the tile loops.
// The tile loops now contain ONLY the 8 DMA fills as VMEM ops, so the
// counted s_waitcnt vmcnt(8) actually keeps the next slot in flight
// (previously in-loop b1/b2 global loads + in-order vmcnt drained the
// prefetch queue every tile, serializing full memory latency per tile).
// ---------------------------------------------------------------------------
__global__ __launch_bounds__(BLK, 2) void k_fused(
    const float* __restrict__ x,
    const unsigned short* __restrict__ w1tf, const float* __restrict__ b1,
    const unsigned short* __restrict__ w2tf, const float* __restrict__ b2,
    const float* __restrict__ W, const int* __restrict__ bounds,
    float* __restrict__ out, int N)
{
  __shared__ float ring[4][2][2048];             // 65,536 B
  __shared__ unsigned short hs4[4][16 * HSTR];   //  5,120 B
  __shared__ float part[4][132];                 //  2,112 B
  __shared__ float meanv[DDIM];                  //    512 B
  __shared__ float tgs[DDIM];                    //    512 B  (73,792 total)

  const int t  = threadIdx.x;
  const int l  = t & 63;
  const int w  = t >> 6;
  const int lr = l & 15;
  const int q  = l >> 4;
  const int g  = blockIdx.x;
  const int lo = bounds[g], hi = bounds[g + 1];
  const int cnt = hi - lo;
  unsigned short* hs = hs4[w];

  if (cnt <= 0) { if (t < DDIM) out[(size_t)g * DDIM + t] = 0.f; return; }

  // ---- weight A-frags in registers (L2-hot 16B loads), ONCE ----
  bf16x8 w1r[2][4], w2r[8];
  #pragma unroll
  for (int mt2 = 0; mt2 < 2; ++mt2)
    #pragma unroll
    for (int kk = 0; kk < 4; ++kk)
      w1r[mt2][kk] = *(const bf16x8*)&w1tf[(size_t)((mt2 * 4 + kk) * 64 + l) * 8];
  #pragma unroll
  for (int mt = 0; mt < 8; ++mt)
    w2r[mt] = *(const bf16x8*)&w2tf[(size_t)(mt * 64 + l) * 8];

  // ---- biases in registers, ONCE (keeps tile loops VMEM-free) ----
  const float4 b1q0 = *(const float4*)(b1 + q * 4);
  const float4 b1q1 = *(const float4*)(b1 + 16 + q * 4);
  float4 b2v[8];
  #pragma unroll
  for (int mt = 0; mt < 8; ++mt)
    b2v[mt] = *(const float4*)(b2 + mt * 16 + q * 4);

  const int sr  = l >> 5;        // stage row parity
  const int sc  = l & 31;        // stage 16B-chunk col
  const int swz = lr & 7;
  const int ntile = (cnt + 15) >> 4;

  // ---- async fill: 8 x global_load_lds(16B), source pre-swizzled ----
  auto fill = [&](int s, int tb) {
    float* lds = ring[w][s];
    #pragma unroll
    for (int j = 0; j < 8; ++j) {
      const int r   = j * 2 + sr;
      const int row = lo + min(tb + r, cnt - 1);      // clamp inside graph
      const int lc  = sc ^ (r & 7);
      __builtin_amdgcn_global_load_lds(x + (size_t)row * DDIM + lc * 4,
                                       lds + j * 256, 16, 0, 0);
    }
  };

  // ---- MLP on one staged tile: y[mt][c] for node lr, d=mt*16+q*4+c ----
  auto mlp = [&](int s, float (&y)[8][4]) {
    float* lds = ring[w][s];
    bf16x8 xf[4];
    #pragma unroll
    for (int kk = 0; kk < 4; ++kk) {
      const int c0 = kk * 8 + q * 2;
      float4 a = *(const float4*)&lds[lr * 128 + ((c0    ) ^ swz) * 4];
      float4 b = *(const float4*)&lds[lr * 128 + ((c0 + 1) ^ swz) * 4];
      uint4 u;
      u.x = pkbf(a.x, a.y); u.y = pkbf(a.z, a.w);
      u.z = pkbf(b.x, b.y); u.w = pkbf(b.z, b.w);
      xf[kk] = *(bf16x8*)&u;
    }
    f32x4 hacc[2];
    hacc[0][0] = b1q0.x; hacc[0][1] = b1q0.y; hacc[0][2] = b1q0.z; hacc[0][3] = b1q0.w;
    hacc[1][0] = b1q1.x; hacc[1][1] = b1q1.y; hacc[1][2] = b1q1.z; hacc[1][3] = b1q1.w;
    #pragma unroll
    for (int kk = 0; kk < 4; ++kk) {
      hacc[0] = __builtin_amdgcn_mfma_f32_16x16x32_bf16(w1r[0][kk], xf[kk], hacc[0], 0, 0, 0);
      hacc[1] = __builtin_amdgcn_mfma_f32_16x16x32_bf16(w1r[1][kk], xf[kk], hacc[1], 0, 0, 0);
    }
    #pragma unroll
    for (int mt2 = 0; mt2 < 2; ++mt2) {
      float h0 = fmaxf(hacc[mt2][0], 0.f), h1 = fmaxf(hacc[mt2][1], 0.f);
      float h2 = fmaxf(hacc[mt2][2], 0.f), h3 = fmaxf(hacc[mt2][3], 0.f);
      uint2 p; p.x = pkbf(h0, h1); p.y = pkbf(h2, h3);
      *(uint2*)&hs[lr * HSTR + mt2 * 16 + q * 4] = p;
    }
    bf16x8 ah = *(const bf16x8*)&hs[lr * HSTR + q * 8];
    f32x4 cacc[8];
    #pragma unroll
    for (int mt = 0; mt < 8; ++mt) {
      cacc[mt][0] = b2v[mt].x; cacc[mt][1] = b2v[mt].y;
      cacc[mt][2] = b2v[mt].z; cacc[mt][3] = b2v[mt].w;
    }
    #pragma unroll
    for (int mt = 0; mt < 8; ++mt)
      cacc[mt] = __builtin_amdgcn_mfma_f32_16x16x32_bf16(w2r[mt], ah, cacc[mt], 0, 0, 0);
    #pragma unroll
    for (int mt = 0; mt < 8; ++mt) {
      float4 xg = *(const float4*)&lds[lr * 128 + ((mt * 4 + q) ^ swz) * 4];
      y[mt][0] = xg.x * (1.f + tanh_fast(cacc[mt][0]));
      y[mt][1] = xg.y * (1.f + tanh_fast(cacc[mt][1]));
      y[mt][2] = xg.z * (1.f + tanh_fast(cacc[mt][2]));
      y[mt][3] = xg.w * (1.f + tanh_fast(cacc[mt][3]));
    }
  };

  // ================= PASS 1: mean accumulate =================
  float macc[8][4];
  #pragma unroll
  for (int mt = 0; mt < 8; ++mt)
    #pragma unroll
    for (int c = 0; c < 4; ++c) macc[mt][c] = 0.f;

  {
    int ti = w, cur = 0;
    if (ti < ntile) fill(cur, ti * 16);
    for (; ti < ntile; ti += 4) {
      const int tn = ti + 4;
      if (tn < ntile) {
        fill(cur ^ 1, tn * 16);
        asm volatile("s_waitcnt vmcnt(8)" ::: "memory");
      } else {
        asm volatile("s_waitcnt vmcnt(0)" ::: "memory");
      }
      float y[8][4];
      mlp(cur, y);
      if (ti * 16 + lr < cnt) {
        #pragma unroll
        for (int mt = 0; mt < 8; ++mt)
          #pragma unroll
          for (int c = 0; c < 4; ++c) macc[mt][c] += y[mt][c];
      }
      cur ^= 1;
    }
  }
  __syncthreads();

  // ---- mean reduce: over lr lanes (xor 1,2,4,8), cross-wave via part ----
  #pragma unroll
  for (int mt = 0; mt < 8; ++mt)
    #pragma unroll
    for (int c = 0; c < 4; ++c) {
      float v = macc[mt][c];
      v += __shfl_xor(v, 1, 64);
      v += __shfl_xor(v, 2, 64);
      v += __shfl_xor(v, 4, 64);
      v += __shfl_xor(v, 8, 64);
      macc[mt][c] = v;
    }
  if (lr == 0) {
    #pragma unroll
    for (int mt = 0; mt < 8; ++mt)
      *(float4*)&part[w][mt * 16 + q * 4] =
          make_float4(macc[mt][0], macc[mt][1], macc[mt][2], macc[mt][3]);
  }
  __syncthreads();
  if (t < DDIM) {
    float m = part[0][t] + part[1][t] + part[2][t] + part[3][t];
    meanv[t] = m / (float)cnt;
  }
  __syncthreads();

  // ---- tg = tanh(mean @ W): 2 thr/col x 64 k, coalesced ----
  {
    const int c = t & 127, s = t >> 7;
    float a = 0.f;
    #pragma unroll 8
    for (int k = 0; k < 64; ++k)
      a = fmaf(meanv[s * 64 + k], W[(size_t)(s * 64 + k) * DDIM + c], a);
    part[s][c] = a;
  }
  __syncthreads();
  if (t < DDIM) tgs[t] = tanh_fast(part[0][t] + part[1][t]);
  __syncthreads();

  // ================= PASS 2: re-stream (L3-hot), coef, out =================
  float oacc[8][4];
  #pragma unroll
  for (int mt = 0; mt < 8; ++mt)
    #pragma unroll
    for (int c = 0; c < 4; ++c) oacc[mt][c] = 0.f;

  // tg fragments to registers once (keep loop VMEM/LDS-light)
  float tgv[8][4];
  #pragma unroll
  for (int mt = 0; mt < 8; ++mt) {
    float4 tv = *(const float4*)&tgs[mt * 16 + q * 4];
    tgv[mt][0] = tv.x; tgv[mt][1] = tv.y; tgv[mt][2] = tv.z; tgv[mt][3] = tv.w;
  }

  {
    int ti = w, cur = 0;
    if (ti < ntile) fill(cur, ti * 16);
    for (; ti < ntile; ti += 4) {
      const int tn = ti + 4;
      if (tn < ntile) {
        fill(cur ^ 1, tn * 16);
        asm volatile("s_waitcnt vmcnt(8)" ::: "memory");
      } else {
        asm volatile("s_waitcnt vmcnt(0)" ::: "memory");
      }
      float y[8][4];
      mlp(cur, y);
      float p = 0.f;
      #pragma unroll
      for (int mt = 0; mt < 8; ++mt) {
        p = fmaf(y[mt][0], tgv[mt][0], p); p = fmaf(y[mt][1], tgv[mt][1], p);
        p = fmaf(y[mt][2], tgv[mt][2], p); p = fmaf(y[mt][3], tgv[mt][3], p);
      }
      p += __shfl_xor(p, 16, 64);
      p += __shfl_xor(p, 32, 64);
      const float coef = sigmoid_fast(p);
      if (ti * 16 + lr < cnt) {
        #pragma unroll
        for (int mt = 0; mt < 8; ++mt)
          #pragma unroll
          for (int c = 0; c < 4; ++c)
            oacc[mt][c] = fmaf(coef, y[mt][c], oacc[mt][c]);
      }
      cur ^= 1;
    }
  }
  __syncthreads();

  // ---- out reduce ----
  #pragma unroll
  for (int mt = 0; mt < 8; ++mt)
    #pragma unroll
    for (int c = 0; c < 4; ++c) {
      float v = oacc[mt][c];
      v += __shfl_xor(v, 1, 64);
      v += __shfl_xor(v, 2, 64);
      v += __shfl_xor(v, 4, 64);
      v += __shfl_xor(v, 8, 64);
      oacc[mt][c] = v;
    }
  if (lr == 0) {
    #pragma unroll
    for (int mt = 0; mt < 8; ++mt)
      *(float4*)&part[w][mt * 16 + q * 4] =
          make_float4(oacc[mt][0], oacc[mt][1], oacc[mt][2], oacc[mt][3]);
  }
  __syncthreads();
  if (t < DDIM)
    out[(size_t)g * DDIM + t] = part[0][t] + part[1][t] + part[2][t] + part[3][t];
}

// ---------------------------------------------------------------------------
extern "C" void kernel_launch(void* const* d_in, const int* in_sizes, int n_in,
                              void* d_out, int out_size, void* d_ws, size_t ws_size,
                              hipStream_t stream) {
  const float* x     = (const float*)d_in[0];
  const int*   batch = (const int*)d_in[1];
  const float* w1 = (const float*)d_in[3];
  const float* b1 = (const float*)d_in[4];
  const float* w2 = (const float*)d_in[5];
  const float* b2 = (const float*)d_in[6];
  const float* W  = (const float*)d_in[7];
  float* out = (float*)d_out;

  const int N = in_sizes[0] / DDIM;
  const int G = out_size / DDIM;

  // ws: [w1tf 4096 u16][w2tf 4096 u16][bounds G+1 int]  (no x2!)
  unsigned short* w1tf = (unsigned short*)d_ws;
  unsigned short* w2tf = w1tf + 4096;
  int* bounds = (int*)(w2tf + 4096);
  (void)ws_size; (void)n_in;

  hipLaunchKernelGGL(k0_prep, dim3(4), dim3(PBLK), 0, stream, w1, w2, w1tf, w2tf);
  hipLaunchKernelGGL(kb_bounds, dim3((G + 1 + PBLK - 1) / PBLK), dim3(PBLK), 0, stream,
                     batch, bounds, N, G);
  hipLaunchKernelGGL(k_fused, dim3(G), dim3(BLK), 0, stream,
                     x, w1tf, b1, w2tf, b2, W, bounds, out, N);
}